// Round 6
// baseline (92.425 us; speedup 1.0000x reference)
//
#include <hip/hip_runtime.h>

// Problem constants (from the reference)
#define B_    8
#define C_    8
#define L_    4096
#define F_    32
#define K_    10
#define PROC_ 20
#define STEP_ 5
#define NW_   815   // len(range(0, L-PROC-STEP+1, STEP)); CHAN_OUT == NW_ (no pad region)

// One DTW: kernel taps kk[] (scalar, block-uniform) vs 20-float window at win.
// 3 VALU ops/cell: v_sub, v_min3, v_fma. Returns acc[K-1][P-1].
__device__ __forceinline__ float dtw_one(const float* __restrict__ win,
                                         const float kk[K_])
{
    float wv[PROC_];
    #pragma unroll
    for (int j = 0; j < PROC_; ++j) wv[j] = win[j];

    float row[PROC_];
    {
        float d = kk[0] - wv[0];
        row[0] = d * d;
        #pragma unroll
        for (int j = 1; j < PROC_; ++j) {
            float dj = kk[0] - wv[j];
            row[j] = fmaf(dj, dj, row[j - 1]);
        }
    }
    #pragma unroll
    for (int i = 1; i < K_; ++i) {
        float diag = row[0];
        float d0 = kk[i] - wv[0];
        float cur = fmaf(d0, d0, diag);
        row[0] = cur;
        float left = cur;
        #pragma unroll
        for (int j = 1; j < PROC_; ++j) {
            float up = row[j];
            float dj = kk[i] - wv[j];
            float m = fminf(fminf(left, up), diag);  // v_min3_f32
            cur = fmaf(dj, dj, m);
            diag = up;
            row[j] = cur;
            left = cur;
        }
    }
    return row[PROC_ - 1];
}

// Identical to round-5 kernel. Launched TWICE to measure its duration k via
// dur_us = F + 2k (idempotent writes, graph-capture safe).
__global__ __launch_bounds__(256, 8) void dtw_kernel(
    const float* __restrict__ x,      // (B, C, L)
    const float* __restrict__ kern,   // (F, K)
    float* __restrict__ out)          // (B, C*F, NW)
{
    __shared__ float sx[L_];

    const int blk = blockIdx.x;          // 0 .. B*C*F-1
    const int f = blk & (F_ - 1);        // fastest
    const int c = (blk >> 5) & (C_ - 1);
    const int b = blk >> 8;

    // Stage x[b][c][:] into LDS with float4 loads (4096 floats = 1024 float4)
    const float4* x4 = reinterpret_cast<const float4*>(x + ((size_t)(b * C_ + c)) * L_);
    float4* s4 = reinterpret_cast<float4*>(sx);
    #pragma unroll
    for (int i = 0; i < L_ / 4 / 256; ++i)
        s4[threadIdx.x + i * 256] = x4[threadIdx.x + i * 256];

    // Kernel taps: block-uniform loads -> s_load / SGPRs
    float kk[K_];
    #pragma unroll
    for (int i = 0; i < K_; ++i) kk[i] = kern[f * K_ + i];

    __syncthreads();

    float* outp = out + ((size_t)b * (C_ * F_) + (c * F_ + f)) * (size_t)NW_;
    const int tid = threadIdx.x;

    // 3 uniform rounds: w = tid, tid+256, tid+512 (max 767 < 815) — no masking.
    #pragma unroll
    for (int r = 0; r < 3; ++r) {
        const int w = tid + r * 256;
        outp[w] = dtw_one(sx + w * STEP_, kk);
    }
    // Masked tail: w = tid + 768, valid iff tid < 47.
    {
        const int w = tid + 768;
        if (w < NW_) outp[w] = dtw_one(sx + w * STEP_, kk);
    }
}

extern "C" void kernel_launch(void* const* d_in, const int* in_sizes, int n_in,
                              void* d_out, int out_size, void* d_ws, size_t ws_size,
                              hipStream_t stream) {
    const float* x    = (const float*)d_in[0];   // (8, 8, 4096) fp32
    const float* kern = (const float*)d_in[1];   // (32, 10) fp32
    float* out        = (float*)d_out;           // (8, 256, 815) fp32

    dim3 grid(B_ * C_ * F_);   // 2048 blocks
    dim3 block(256);
    // DOUBLE LAUNCH — timing probe: dur_us = F_fixed + 2*k_kernel.
    // Second launch is idempotent (writes identical values).
    hipLaunchKernelGGL(dtw_kernel, grid, block, 0, stream, x, kern, out);
    hipLaunchKernelGGL(dtw_kernel, grid, block, 0, stream, x, kern, out);
}

// Round 7
// 73.383 us; speedup vs baseline: 1.2595x; 1.2595x over previous
//
#include <hip/hip_runtime.h>

// Problem constants (from the reference)
#define B_    8
#define C_    8
#define L_    4096
#define F_    32
#define K_    10
#define PROC_ 20
#define STEP_ 5
#define NW_   815   // len(range(0, L-PROC-STEP+1, STEP)); CHAN_OUT == NW_ (no pad region)

// One DTW: kernel taps kk[] (scalar, block-uniform) vs 20-float window at win.
// 3 VALU ops/cell: v_sub, v_min3, v_fma — minimal for the in-register
// recurrence. Measured kernel duration: 18.4 us (double-launch probe, r6),
// = 68% of the saturated-VALU-issue model (12.6 us). Packed f32 (r2) and
// packed f16 (r4) variants both measured SLOWER (k~24-25 us): packed ops
// are not full-rate wins on this VALU and cost registers/conversions.
__device__ __forceinline__ float dtw_one(const float* __restrict__ win,
                                         const float kk[K_])
{
    float wv[PROC_];
    #pragma unroll
    for (int j = 0; j < PROC_; ++j) wv[j] = win[j];

    float row[PROC_];
    {
        float d = kk[0] - wv[0];
        row[0] = d * d;
        #pragma unroll
        for (int j = 1; j < PROC_; ++j) {
            float dj = kk[0] - wv[j];
            row[j] = fmaf(dj, dj, row[j - 1]);
        }
    }
    #pragma unroll
    for (int i = 1; i < K_; ++i) {
        float diag = row[0];
        float d0 = kk[i] - wv[0];
        float cur = fmaf(d0, d0, diag);
        row[0] = cur;
        float left = cur;
        #pragma unroll
        for (int j = 1; j < PROC_; ++j) {
            float up = row[j];
            float dj = kk[i] - wv[j];
            float m = fminf(fminf(left, up), diag);  // v_min3_f32
            cur = fmaf(dj, dj, m);
            diag = up;
            row[j] = cur;
            left = cur;
        }
    }
    return row[PROC_ - 1];
}

// 8 waves/SIMD (64-VGPR cap): state wv[20]+row[20]=40 VGPR, kk -> SGPRs.
// 2048 blocks = 8 blocks/CU exactly; issue-saturated at this occupancy.
__global__ __launch_bounds__(256, 8) void dtw_kernel(
    const float* __restrict__ x,      // (B, C, L)
    const float* __restrict__ kern,   // (F, K)
    float* __restrict__ out)          // (B, C*F, NW)
{
    __shared__ float sx[L_];

    const int blk = blockIdx.x;          // 0 .. B*C*F-1
    const int f = blk & (F_ - 1);        // fastest
    const int c = (blk >> 5) & (C_ - 1);
    const int b = blk >> 8;

    // Stage x[b][c][:] into LDS with float4 loads (4096 floats = 1024 float4)
    const float4* x4 = reinterpret_cast<const float4*>(x + ((size_t)(b * C_ + c)) * L_);
    float4* s4 = reinterpret_cast<float4*>(sx);
    #pragma unroll
    for (int i = 0; i < L_ / 4 / 256; ++i)
        s4[threadIdx.x + i * 256] = x4[threadIdx.x + i * 256];

    // Kernel taps: block-uniform loads -> SGPRs
    float kk[K_];
    #pragma unroll
    for (int i = 0; i < K_; ++i) kk[i] = kern[f * K_ + i];

    __syncthreads();

    float* outp = out + ((size_t)b * (C_ * F_) + (c * F_ + f)) * (size_t)NW_;
    const int tid = threadIdx.x;

    // 3 uniform rounds: w = tid, tid+256, tid+512 (max 767 < 815) — no masking.
    #pragma unroll
    for (int r = 0; r < 3; ++r) {
        const int w = tid + r * 256;
        outp[w] = dtw_one(sx + w * STEP_, kk);
    }
    // Masked tail: w = tid + 768, valid iff tid < 47 (wave 0 only; waves 1-3
    // skip via execz — cheaper than rebalancing, straggler absorbed by the
    // 8-blocks/CU co-residency).
    {
        const int w = tid + 768;
        if (w < NW_) outp[w] = dtw_one(sx + w * STEP_, kk);
    }
}

extern "C" void kernel_launch(void* const* d_in, const int* in_sizes, int n_in,
                              void* d_out, int out_size, void* d_ws, size_t ws_size,
                              hipStream_t stream) {
    const float* x    = (const float*)d_in[0];   // (8, 8, 4096) fp32
    const float* kern = (const float*)d_in[1];   // (32, 10) fp32
    float* out        = (float*)d_out;           // (8, 256, 815) fp32

    dim3 grid(B_ * C_ * F_);   // 2048 blocks
    dim3 block(256);
    hipLaunchKernelGGL(dtw_kernel, grid, block, 0, stream, x, kern, out);
}